// Round 3
// baseline (796.027 us; speedup 1.0000x reference)
//
#include <hip/hip_runtime.h>

// LocallyConnectedLayer: out[b,o,p] = bias[p,o] + sum_k x_patch[b,k,p] * W[p,o,k]
// B=32 C=96 H=W=32 OC=96 k=3 s=1 -> oh=ow=30, P=900, K=864.
//
// Round-3 design (post-mortem: round 2 was LDS-BW bound at 4 B/FMA = 120us floor):
//  - W streamed global->register, never staged: each W float4 read by exactly one
//    wave-instruction (16 lanes broadcast) -> zero duplication, coalesced-enough
//    (4 distinct 64B lines per instr, each line fully consumed over 4 kq steps).
//  - A (patches) in LDS only: 1 B/FMA -> 30us LDS floor. Conflict-free staging
//    (bank = (4rm+b)%32, 2-way max across wave halves = free) and reads
//    (16 float2 span all 32 banks once).
//  - o-split x2 -> 1800 blocks, LDS 15.6KB -> 10 blocks/CU cap, ~7 resident avg.
//  - XCD-chunked swizzle (1800%8==0): 225 consecutive (oh,p) per XCD -> the 16
//    p-writers of each 64B out line share one L2 -> write combining (round-2
//    WRITE_SIZE was 110MB vs 11MB ideal); x slice per XCD ~3.9MB fits L2.
//  - T14: next chunk's x loads issued before compute, land at next ds_write.

namespace {
constexpr int CIN   = 96;
constexpr int HW_   = 1024;          // 32*32
constexpr int CSTR  = CIN * HW_;     // x batch stride
constexpr int OC    = 96;
constexpr int OW    = 30;
constexpr int NP    = 900;
constexpr int KTOT  = 864;
constexpr int KC    = 108;           // k-chunk
constexpr int NCH   = KTOT / KC;     // 8
constexpr int NTHR  = 192;           // 3 waves
constexpr int APAD  = 36;
constexpr int OBLK  = 48;            // o per block (2-way o-split)
constexpr int NBLK  = NP * 2;        // 1800
constexpr int CHUNK = NBLK / 8;      // 225 blocks per XCD
}

__global__ __launch_bounds__(NTHR, 5)
void lc_forward(const float* __restrict__ x,
                const float* __restrict__ weight,
                const float* __restrict__ bias,
                float* __restrict__ out)
{
    __shared__ float Alds[KC][APAD];   // [k][b], 15.6 KB

    // XCD-aware bijective swizzle: consecutive swz -> same XCD
    const int bid = blockIdx.x;
    const int swz = (bid & 7) * CHUNK + (bid >> 3);
    const int oh  = swz / NP;          // 0..1
    const int p   = swz - oh * NP;     // 0..899
    const int pi  = p / OW;
    const int pj  = p - pi * OW;

    const int t    = threadIdx.x;
    const int lane = t & 63;
    const int wv   = t >> 6;           // 0..2

    // compute mapping: tile 2b x 4o
    const int b0  = (lane & 15) * 2;             // 0,2,...,30
    const int og  = wv * 4 + (lane >> 4);        // 0..11, unique per (wave,quarter)
    const int o0g = oh * OBLK + og * 4;          // global o base (4 consecutive rows)

    // staging mapping: b = t%32, rm = t/32 + 6j -> conflict-free ds_writes
    const int bs  = t & 31;
    const int rm0 = t >> 5;                      // 0..5

    const float* xb    = x + (size_t)bs * CSTR + pi * 32 + pj;
    const float* wbase = weight + ((size_t)p * OC + o0g) * KTOT;

    float acc0[4] = {0.f, 0.f, 0.f, 0.f};
    float acc1[4] = {0.f, 0.f, 0.f, 0.f};
    float xr[18];

#define LOADX(CH)                                         \
    {                                                     \
        _Pragma("unroll")                                 \
        for (int j = 0; j < 18; ++j) {                    \
            const int ka = (CH) * KC + rm0 + 6 * j;       \
            const int c  = ka / 9;                        \
            const int r  = ka - c * 9;                    \
            const int di = r / 3;                         \
            const int dj = r - di * 3;                    \
            xr[j] = xb[c * HW_ + di * 32 + dj];           \
        }                                                 \
    }

    LOADX(0);

    for (int ch = 0; ch < NCH; ++ch) {
        __syncthreads();                       // prev-chunk readers done
        #pragma unroll
        for (int j = 0; j < 18; ++j)
            Alds[rm0 + 6 * j][bs] = xr[j];
        __syncthreads();
        if (ch < NCH - 1) LOADX(ch + 1);       // in flight across compute

        const float* wch = wbase + ch * KC;
        #pragma unroll
        for (int kq = 0; kq < KC / 4; ++kq) {  // 27 steps of 4 k
            const float4 w0 = *reinterpret_cast<const float4*>(wch + 0 * KTOT + kq * 4);
            const float4 w1 = *reinterpret_cast<const float4*>(wch + 1 * KTOT + kq * 4);
            const float4 w2 = *reinterpret_cast<const float4*>(wch + 2 * KTOT + kq * 4);
            const float4 w3 = *reinterpret_cast<const float4*>(wch + 3 * KTOT + kq * 4);
            const float2 a0 = *reinterpret_cast<const float2*>(&Alds[kq * 4 + 0][b0]);
            const float2 a1 = *reinterpret_cast<const float2*>(&Alds[kq * 4 + 1][b0]);
            const float2 a2 = *reinterpret_cast<const float2*>(&Alds[kq * 4 + 2][b0]);
            const float2 a3 = *reinterpret_cast<const float2*>(&Alds[kq * 4 + 3][b0]);
#define COLJ(J, WJ)                                                         \
            acc0[J] = fmaf(a0.x, WJ.x, acc0[J]);                            \
            acc1[J] = fmaf(a0.y, WJ.x, acc1[J]);                            \
            acc0[J] = fmaf(a1.x, WJ.y, acc0[J]);                            \
            acc1[J] = fmaf(a1.y, WJ.y, acc1[J]);                            \
            acc0[J] = fmaf(a2.x, WJ.z, acc0[J]);                            \
            acc1[J] = fmaf(a2.y, WJ.z, acc1[J]);                            \
            acc0[J] = fmaf(a3.x, WJ.w, acc0[J]);                            \
            acc1[J] = fmaf(a3.y, WJ.w, acc1[J]);
            COLJ(0, w0)
            COLJ(1, w1)
            COLJ(2, w2)
            COLJ(3, w3)
#undef COLJ
        }
    }

    // epilogue: bias + store (L2 write-combining via XCD-local p neighbors)
    const float* bp = bias + (size_t)p * OC + o0g;
    #pragma unroll
    for (int j = 0; j < 4; ++j) {
        const float bb = bp[j];
        out[((size_t)(b0 + 0) * OC + o0g + j) * NP + p] = acc0[j] + bb;
        out[((size_t)(b0 + 1) * OC + o0g + j) * NP + p] = acc1[j] + bb;
    }
#undef LOADX
}

extern "C" void kernel_launch(void* const* d_in, const int* in_sizes, int n_in,
                              void* d_out, int out_size, void* d_ws, size_t ws_size,
                              hipStream_t stream) {
    const float* x  = (const float*)d_in[0];
    const float* w  = (const float*)d_in[1];
    const float* bi = (const float*)d_in[2];
    float* o        = (float*)d_out;
    lc_forward<<<dim3(NBLK), dim3(NTHR), 0, stream>>>(x, w, bi, o);
}

// Round 4
// 578.636 us; speedup vs baseline: 1.3757x; 1.3757x over previous
//
#include <hip/hip_runtime.h>

// LocallyConnectedLayer via bf16 MFMA with fused f32->bf16 conversion.
// out[b,o,p] = bias[p,o] + sum_k patches[b,k,p] * W[p,o,k]
// B=32 C=96 H=W=32 OC=96 -> oh=ow=30, P=900, K=864.
//
// Round-4 post-mortem-driven design:
//  - Round 3 proved broadcast-W-from-global is latency-bound (VALUBusy 14%).
//    Here W feeds MFMA B-fragments directly: per wave-instr 16 o-rows x 128
//    contiguous bytes, every line fully consumed, W (298.6 MB) read once.
//  - Compute via mfma_f32_16x16x32_bf16 (threshold 2.9e-2 is bf16-tolerant;
//    f32 baseline absmax was 3.9e-3). MFMA total ~2.3us -> pure streaming kernel.
//  - A (x patches) staged per 288-k chunk into LDS in FRAGMENT-LINEAR bf16
//    order: compute ds_read_b128 conflict-free by construction.
//  - Write amplification fix (round 2: 110 MB, round 3: 268 MB vs 11 ideal):
//    kernel1 stores ws[p][b][o] (full lines, block-contiguous); kernel2 does a
//    64x64 LDS transpose to out[b][o][p] with coalesced loads AND stores.

namespace {
constexpr int CIN  = 96;
constexpr int HW_  = 1024;           // 32*32
constexpr int CSTR = CIN * HW_;
constexpr int OC   = 96;
constexpr int OW   = 30;
constexpr int NP   = 900;
constexpr int KTOT = 864;
constexpr int KC   = 288;            // 32 channels * 9 taps per chunk
constexpr int NCH  = KTOT / KC;      // 3
constexpr int NTHR = 192;            // 3 waves
constexpr int NBLK = NP * 2;         // p x o-half
}

typedef __attribute__((ext_vector_type(8))) short   bf16x8;
typedef __attribute__((ext_vector_type(4))) float   f32x4;

__device__ __forceinline__ unsigned short f2bf(float f) {
    unsigned u = __builtin_bit_cast(unsigned, f);
    u += 0x7fffu + ((u >> 16) & 1u);             // RNE
    return (unsigned short)(u >> 16);
}

__global__ __launch_bounds__(NTHR, 6)
void lc_mfma(const float* __restrict__ x, const float* __restrict__ weight,
             const float* __restrict__ bias, float* __restrict__ ws)
{
    // fragment-linear A chunk: [step 0..8][mtile 0..1][lane 0..63][8 bf16] = 18432 B
    __shared__ unsigned Albuf[9 * 2 * 64 * 4];

    const int bid = blockIdx.x;
    const int p   = bid >> 1;
    const int oh  = bid & 1;
    const int pi  = p / OW;
    const int pj  = p - pi * OW;

    const int t    = threadIdx.x;
    const int lane = t & 63;
    const int wv   = t >> 6;                     // n-tile of this wave

    // ---- compute-phase mapping (MFMA fragments) ----
    const int nlane = lane & 15;                 // n within 16-tile
    const int kq    = lane >> 4;                 // k-quarter 0..3
    const int o_ln  = oh * 48 + wv * 16 + nlane; // this lane's o row
    const float* wrow = weight + ((size_t)p * OC + o_ln) * KTOT + (kq << 3);
    const float  bb   = bias[(size_t)p * OC + o_ln];

    // ---- staging mapping ----
    const int bs   = t & 31;                     // batch
    const int kset = t >> 5;                     // 0..5
    const int mt_s = bs >> 4;
    const int bl   = bs & 15;
    const float* xb = x + (size_t)bs * CSTR + pi * 32 + pj;

    f32x4 acc0 = {0.f, 0.f, 0.f, 0.f};
    f32x4 acc1 = {0.f, 0.f, 0.f, 0.f};

    for (int ch = 0; ch < NCH; ++ch) {
        if (ch) __syncthreads();                 // prev-chunk readers done
        // ---- stage 288 k (32 channels) as bf16 pairs into frag-linear LDS ----
        const float* xc = xb + ch * 32 * HW_;
        #pragma unroll 6
        for (int j = 0; j < 24; ++j) {
            const int kk = 2 * kset + 12 * j;    // even, 0..286
            const int k1 = kk + 1;
            const int c0 = kk / 9, r0 = kk - 9 * c0, di0 = r0 / 3, dj0 = r0 - 3 * di0;
            const int c1 = k1 / 9, r1 = k1 - 9 * c1, di1 = r1 / 3, dj1 = r1 - 3 * di1;
            const float f0 = xc[c0 * HW_ + di0 * 32 + dj0];
            const float f1 = xc[c1 * HW_ + di1 * 32 + dj1];
            const int s  = kk >> 5;              // step in chunk
            const int ke = kk & 31;
            const int lw = bl + ((ke >> 3) << 4);
            const int e  = ke & 7;               // even
            const int off = (((s * 2 + mt_s) * 64 + lw) << 3) + e;  // short index
            Albuf[off >> 1] = (unsigned)f2bf(f0) | ((unsigned)f2bf(f1) << 16);
        }
        __syncthreads();

        // ---- 9 MFMA k-steps; B-fragment streamed from global + cvt ----
        const bf16x8* Afr = (const bf16x8*)Albuf;
        #pragma unroll 3
        for (int s = 0; s < 9; ++s) {
            const int ks = ch * 9 + s;
            const float4 wlo = *(const float4*)(wrow + ks * 32);
            const float4 whi = *(const float4*)(wrow + ks * 32 + 4);
            bf16x8 bfr;
            bfr[0] = (short)f2bf(wlo.x); bfr[1] = (short)f2bf(wlo.y);
            bfr[2] = (short)f2bf(wlo.z); bfr[3] = (short)f2bf(wlo.w);
            bfr[4] = (short)f2bf(whi.x); bfr[5] = (short)f2bf(whi.y);
            bfr[6] = (short)f2bf(whi.z); bfr[7] = (short)f2bf(whi.w);
            const bf16x8 a0 = Afr[(s * 2 + 0) * 64 + lane];
            const bf16x8 a1 = Afr[(s * 2 + 1) * 64 + lane];
            acc0 = __builtin_amdgcn_mfma_f32_16x16x32_bf16(a0, bfr, acc0, 0, 0, 0);
            acc1 = __builtin_amdgcn_mfma_f32_16x16x32_bf16(a1, bfr, acc1, 0, 0, 0);
        }
    }

    // ---- epilogue: ws[p][b][o], full-line coalesced stores ----
    float* wsp = ws + (size_t)p * (32 * OC);
    #pragma unroll
    for (int r = 0; r < 4; ++r) {
        const int brow = (kq << 2) + r;          // D row = (lane>>4)*4 + reg
        wsp[(size_t)brow * OC + o_ln]        = acc0[r] + bb;
        wsp[(size_t)(16 + brow) * OC + o_ln] = acc1[r] + bb;
    }
}

// ws [900][3072] -> out [3072][900], 64x64 LDS tiles
__global__ __launch_bounds__(256)
void lc_transpose(const float* __restrict__ ws, float* __restrict__ out)
{
    __shared__ float tile[64][65];
    const int bo0 = blockIdx.x * 64;
    const int p0  = blockIdx.y * 64;
    const int tx  = threadIdx.x & 63;
    const int ty  = threadIdx.x >> 6;            // 0..3

    #pragma unroll
    for (int i = 0; i < 16; ++i) {
        const int pp = i * 4 + ty;
        if (p0 + pp < NP)
            tile[pp][tx] = ws[(size_t)(p0 + pp) * 3072 + bo0 + tx];
    }
    __syncthreads();
    #pragma unroll
    for (int i = 0; i < 16; ++i) {
        const int bb = i * 4 + ty;
        if (p0 + tx < NP)
            out[(size_t)(bo0 + bb) * NP + p0 + tx] = tile[tx][bb];
    }
}

extern "C" void kernel_launch(void* const* d_in, const int* in_sizes, int n_in,
                              void* d_out, int out_size, void* d_ws, size_t ws_size,
                              hipStream_t stream) {
    const float* x  = (const float*)d_in[0];
    const float* w  = (const float*)d_in[1];
    const float* bi = (const float*)d_in[2];
    float* out      = (float*)d_out;
    float* ws       = (float*)d_ws;              // 900*3072*4 = 11.06 MB

    lc_mfma<<<dim3(NBLK), dim3(NTHR), 0, stream>>>(x, w, bi, ws);
    lc_transpose<<<dim3(3072 / 64, (NP + 63) / 64), dim3(256), 0, stream>>>(ws, out);
}

// Round 5
// 535.393 us; speedup vs baseline: 1.4868x; 1.0808x over previous
//
#include <hip/hip_runtime.h>

// LocallyConnectedLayer via bf16 MFMA, fused f32->bf16, burst-prefetched streaming.
// out[b,o,p] = bias[p,o] + sum_k patches[b,k,p] * W[p,o,k]
// B=32 C=96 H=W=32 OC=96 -> oh=ow=30, P=900, K=864.
//
// Round-5 (post-mortem of r4: VGPR=40, VALUBusy 11% -> latency-bound, no MLP):
//  - KC=96 chunks (3 MFMA k-steps). Per chunk each lane: 6x float4 W burst +
//    16 x-gathers, ALL issued at the end of the previous iteration (T14),
//    consumed after the next barrier. Eager f32->bf16 cvt frees the f32 regs
//    before the next burst -> no double allocation (~110 VGPR, cap 128).
//  - A staged as 2x ds_write_b128 per thread (contiguous uint4), conflict-free
//    both phases (r4 had 2.3M conflicts from dword column writes).
//  - A double-buffered in LDS -> ONE __syncthreads per chunk.
//  - Keeps r4's validated pieces: fragment layout, epilogue ws[p][b][o]
//    (WRITE_SIZE 10.8MB ok), 64x64 transpose kernel.

namespace {
constexpr int CIN  = 96;
constexpr int HW_  = 1024;           // 32*32
constexpr int CSTR = CIN * HW_;
constexpr int OC   = 96;
constexpr int OW   = 30;
constexpr int NP   = 900;
constexpr int KTOT = 864;
constexpr int KC   = 96;             // chunk: 3 MFMA k-steps
constexpr int NCH  = KTOT / KC;      // 9
constexpr int NTHR = 192;            // 3 waves
constexpr int NBLK = NP * 2;         // p x o-half
}

typedef __attribute__((ext_vector_type(8))) short bf16x8;
typedef __attribute__((ext_vector_type(4))) float f32x4;

__device__ __forceinline__ unsigned f2bf_pk(float lo, float hi) {
    unsigned ul = __builtin_bit_cast(unsigned, lo);
    unsigned uh = __builtin_bit_cast(unsigned, hi);
    ul += 0x7fffu + ((ul >> 16) & 1u);           // RNE
    uh += 0x7fffu + ((uh >> 16) & 1u);
    return (ul >> 16) | (uh & 0xffff0000u);
}

__global__ __launch_bounds__(NTHR, 4)
void lc_mfma(const float* __restrict__ x, const float* __restrict__ weight,
             const float* __restrict__ bias, float* __restrict__ ws)
{
    __shared__ uint4 Albuf[2][384];              // [buf][(s*2+mt)*64 + lw], 12.3 KB

    const int bid = blockIdx.x;
    const int p   = bid >> 1;
    const int oh  = bid & 1;
    const int pi  = p / OW;
    const int pj  = p - pi * OW;

    const int t = threadIdx.x, lane = t & 63, wv = t >> 6;

    // ---- MFMA fragment mapping (validated in round 4) ----
    const int nlane = lane & 15;
    const int kq    = lane >> 4;                 // k-quarter
    const int o_ln  = oh * 48 + wv * 16 + nlane;
    const float* wrow = weight + ((size_t)p * OC + o_ln) * KTOT + (kq << 3);
    const float  bb   = bias[(size_t)p * OC + o_ln];

    // ---- staging mapping: thread owns batch bs, k-range [16*kset, 16*kset+16) ----
    const int bs = t & 31, kset = t >> 5;        // kset 0..5
    const int mt = bs >> 4, bl = bs & 15;
    const float* xb = x + (size_t)bs * CSTR + pi * 32 + pj;

    int wr_idx[2];                               // uint4 indices, constant across chunks
    #pragma unroll
    for (int w = 0; w < 2; ++w) {
        const int kk0 = 16 * kset + 8 * w;       // chunk-local even base
        wr_idx[w] = ((kk0 >> 5) * 2 + mt) * 64 + bl + (((kk0 & 31) >> 3) << 4);
    }

    f32x4 acc0 = {0.f, 0.f, 0.f, 0.f};
    f32x4 acc1 = {0.f, 0.f, 0.f, 0.f};

    float  xf[16];                               // raw x burst (consumed next iter)
    float4 wn[6];                                // raw W burst (consumed next iter)

#define XLOAD(CH)                                               \
    _Pragma("unroll")                                           \
    for (int d = 0; d < 16; ++d) {                              \
        const int k  = (CH) * KC + 16 * kset + d;               \
        const int c  = k / 9;                                   \
        const int r  = k - 9 * c;                               \
        const int di = r / 3;                                   \
        const int dj = r - 3 * di;                              \
        xf[d] = xb[c * HW_ + di * 32 + dj];                     \
    }

#define WLOAD(CH)                                                        \
    _Pragma("unroll")                                                    \
    for (int s = 0; s < 3; ++s) {                                        \
        wn[2 * s]     = *(const float4*)(wrow + (CH) * KC + s * 32);     \
        wn[2 * s + 1] = *(const float4*)(wrow + (CH) * KC + s * 32 + 4); \
    }

    XLOAD(0)
    WLOAD(0)

    #pragma unroll
    for (int ch = 0; ch < NCH; ++ch) {
        // (b) pack & stage A chunk: two conflict-free ds_write_b128
        const uint4 v0 = {f2bf_pk(xf[0], xf[1]),  f2bf_pk(xf[2], xf[3]),
                          f2bf_pk(xf[4], xf[5]),  f2bf_pk(xf[6], xf[7])};
        const uint4 v1 = {f2bf_pk(xf[8], xf[9]),  f2bf_pk(xf[10], xf[11]),
                          f2bf_pk(xf[12], xf[13]), f2bf_pk(xf[14], xf[15])};
        Albuf[ch & 1][wr_idx[0]] = v0;
        Albuf[ch & 1][wr_idx[1]] = v1;

        // (c) eager W cvt -> frees wn before the next burst
        unsigned wb[12];
        #pragma unroll
        for (int s = 0; s < 3; ++s) {
            wb[4 * s + 0] = f2bf_pk(wn[2 * s].x,     wn[2 * s].y);
            wb[4 * s + 1] = f2bf_pk(wn[2 * s].z,     wn[2 * s].w);
            wb[4 * s + 2] = f2bf_pk(wn[2 * s + 1].x, wn[2 * s + 1].y);
            wb[4 * s + 3] = f2bf_pk(wn[2 * s + 1].z, wn[2 * s + 1].w);
        }

        // (d) burst-prefetch next chunk (22 independent loads in flight)
        if (ch < NCH - 1) { XLOAD(ch + 1) WLOAD(ch + 1) }

        // (e) one barrier per chunk (A double-buffered)
        __syncthreads();

        // (f) 3 MFMA k-steps from LDS + converted W regs
        const bf16x8* Af = reinterpret_cast<const bf16x8*>(&Albuf[ch & 1][0]);
        #pragma unroll
        for (int s = 0; s < 3; ++s) {
            const bf16x8 bfr = __builtin_bit_cast(bf16x8,
                (uint4){wb[4 * s], wb[4 * s + 1], wb[4 * s + 2], wb[4 * s + 3]});
            const bf16x8 a0 = Af[(s * 2 + 0) * 64 + lane];
            const bf16x8 a1 = Af[(s * 2 + 1) * 64 + lane];
            acc0 = __builtin_amdgcn_mfma_f32_16x16x32_bf16(a0, bfr, acc0, 0, 0, 0);
            acc1 = __builtin_amdgcn_mfma_f32_16x16x32_bf16(a1, bfr, acc1, 0, 0, 0);
        }
    }
#undef XLOAD
#undef WLOAD

    // ---- epilogue: ws[p][b][o], full-line coalesced stores (validated r4) ----
    float* wsp = ws + (size_t)p * (32 * OC);
    #pragma unroll
    for (int r = 0; r < 4; ++r) {
        const int brow = (kq << 2) + r;
        wsp[(size_t)brow * OC + o_ln]        = acc0[r] + bb;
        wsp[(size_t)(16 + brow) * OC + o_ln] = acc1[r] + bb;
    }
}

// ws [900][3072] -> out [3072][900], 64x64 LDS tiles (validated r4)
__global__ __launch_bounds__(256)
void lc_transpose(const float* __restrict__ ws, float* __restrict__ out)
{
    __shared__ float tile[64][65];
    const int bo0 = blockIdx.x * 64;
    const int p0  = blockIdx.y * 64;
    const int tx  = threadIdx.x & 63;
    const int ty  = threadIdx.x >> 6;

    #pragma unroll
    for (int i = 0; i < 16; ++i) {
        const int pp = i * 4 + ty;
        if (p0 + pp < NP)
            tile[pp][tx] = ws[(size_t)(p0 + pp) * 3072 + bo0 + tx];
    }
    __syncthreads();
    #pragma unroll
    for (int i = 0; i < 16; ++i) {
        const int bb = i * 4 + ty;
        if (p0 + tx < NP)
            out[(size_t)(bo0 + bb) * NP + p0 + tx] = tile[tx][bb];
    }
}

extern "C" void kernel_launch(void* const* d_in, const int* in_sizes, int n_in,
                              void* d_out, int out_size, void* d_ws, size_t ws_size,
                              hipStream_t stream) {
    const float* x  = (const float*)d_in[0];
    const float* w  = (const float*)d_in[1];
    const float* bi = (const float*)d_in[2];
    float* out      = (float*)d_out;
    float* ws       = (float*)d_ws;              // 900*3072*4 = 11.06 MB

    lc_mfma<<<dim3(NBLK), dim3(NTHR), 0, stream>>>(x, w, bi, ws);
    lc_transpose<<<dim3(3072 / 64, (NP + 63) / 64), dim3(256), 0, stream>>>(ws, out);
}

// Round 7
// 450.121 us; speedup vs baseline: 1.7685x; 1.1894x over previous
//
#include <hip/hip_runtime.h>

// LocallyConnectedLayer: out[b,o,p] = bias[p,o] + sum_k patches[b,k,p]*W[p,o,k]
// B=32 C=96 H=W=32 OC=96 k=3 -> oh=ow=30, P=900, K=864.
//
// Round-6: kill the x gather-transaction storm (r5: ~50M line-requests, 64
// lines/instr -> latency+VMEM-pipe bound at 13% HBM, VALUBusy 11%).
//  - lc_im2col: amortize the unfold ONCE. Coalesced x row reads -> LDS (bf16)
//    -> write Acols in the exact MFMA fragment-linear layout (validated r4/r5),
//    1KB-contiguous blobs per wave. 12.6 MB in, 49.8 MB out.
//  - lc_mfma6: one block per p (384 thr, 6 waves, 96 o). A via
//    global_load_lds dwordx4 (linear both sides, cannot be sunk past barrier),
//    double-buffered 288-k chunks. W fragment-direct float4 (line-efficient,
//    read exactly once). 360 MB total -> ~60us HBM floor.
//  - epilogue ws2[p][b][o] + 64x64 transpose (validated: WRITE_SIZE 10.8 MB).
//  - ws fallback: if ws_size < 61 MB run the r5 self-contained path.

namespace {
constexpr int CIN  = 96;
constexpr int HW_  = 1024;
constexpr int CSTR = CIN * HW_;      // 98304
constexpr int OC   = 96;
constexpr int OW   = 30;
constexpr int NP   = 900;
constexpr int KTOT = 864;
constexpr size_t ACOLS_U4    = (size_t)NP * 3456;          // uint4 count
constexpr size_t ACOLS_BYTES = ACOLS_U4 * 16;              // 49,766,400
constexpr size_t WS2_BYTES   = (size_t)NP * 32 * OC * 4;   // 11,059,200
}

typedef __attribute__((ext_vector_type(8))) short bf16x8;
typedef __attribute__((ext_vector_type(4))) float f32x4;

__device__ __forceinline__ unsigned f2bf_pk(float lo, float hi) {
    unsigned ul = __builtin_bit_cast(unsigned, lo);
    unsigned uh = __builtin_bit_cast(unsigned, hi);
    ul += 0x7fffu + ((ul >> 16) & 1u);           // RNE
    uh += 0x7fffu + ((uh >> 16) & 1u);
    return (ul >> 16) | (uh & 0xffff0000u);
}

// ---------------------------------------------------------------------------
// Kernel 1: im2col into fragment-linear bf16 Acols[p][s][mt][lane][8]
// blocks: 360 = pi(30) x pjh(2) x mt(2) x cch(3); 256 threads
// ---------------------------------------------------------------------------
__global__ __launch_bounds__(256, 2)
void lc_im2col(const float* __restrict__ x, uint4* __restrict__ Acols)
{
    __shared__ unsigned short Xl[16 * 1924];     // [bl][(c*3+di)*20 + wl], 61.6 KB
    unsigned* Xl32 = (unsigned*)Xl;

    const int bid = blockIdx.x;
    const int pjh = bid & 1;
    const int mt  = (bid >> 1) & 1;
    const int cch = (bid >> 2) % 3;
    const int pi  = bid / 12;
    const int c0  = cch * 32;
    const int w0e = pjh ? 12 : 0;                // even w window base (20 wide)
    const int pj0 = pjh * 15;

    const int t = threadIdx.x, lane = t & 63, wv = t >> 6;

    // ---- stage: x[mt*16+bl][c0+c][pi+di][w0e..w0e+19] -> bf16 pairs in LDS ----
    for (int it = 0; it < 60; ++it) {
        const int T   = t + it * 256;            // 0..15359
        const int row = T / 10;                  // (bl*32+c)*3+di
        const int pr  = T - row * 10;
        const int bl  = row / 96;
        const int rem = row - bl * 96;
        const int c   = rem / 3;
        const int di  = rem - c * 3;
        const float2 v = *(const float2*)(x + (size_t)(mt * 16 + bl) * CSTR
                             + (c0 + c) * HW_ + (pi + di) * 32 + w0e + 2 * pr);
        Xl32[bl * 962 + (c * 3 + di) * 10 + pr] = f2bf_pk(v.x, v.y);
    }
    __syncthreads();

    // ---- gather + 1KB-contiguous blob writes ----
    const int khi = lane >> 4, bl = lane & 15;
    for (int sl = 0; sl < 9; ++sl) {
        int off[8];
        #pragma unroll
        for (int e = 0; e < 8; ++e) {
            const int kl = 32 * sl + 8 * khi + e;    // chunk-local k, <288
            const int c  = (kl * 57) >> 9;           // exact /9 for kl<288
            const int r  = kl - 9 * c;
            const int di = (r * 11) >> 5;            // exact /3 for r<9
            const int dj = r - 3 * di;
            off[e] = bl * 1924 + (c * 3 + di) * 20 + dj - w0e;
        }
        const int s = cch * 9 + sl;
        for (int pjl = wv; pjl < 15; pjl += 4) {
            const int pj = pj0 + pjl;
            const int p  = pi * OW + pj;
            unsigned short v0 = Xl[off[0] + pj], v1 = Xl[off[1] + pj];
            unsigned short v2 = Xl[off[2] + pj], v3 = Xl[off[3] + pj];
            unsigned short v4 = Xl[off[4] + pj], v5 = Xl[off[5] + pj];
            unsigned short v6 = Xl[off[6] + pj], v7 = Xl[off[7] + pj];
            uint4 u;
            u.x = v0 | ((unsigned)v1 << 16);
            u.y = v2 | ((unsigned)v3 << 16);
            u.z = v4 | ((unsigned)v5 << 16);
            u.w = v6 | ((unsigned)v7 << 16);
            Acols[(size_t)((p * 27 + s) * 2 + mt) * 64 + lane] = u;
        }
    }
}

// ---------------------------------------------------------------------------
// Kernel 2: main GEMM. 900 blocks (one per p), 384 thr (6 waves, 16 o each).
// ---------------------------------------------------------------------------
__global__ __launch_bounds__(384, 3)
void lc_mfma6(const float* __restrict__ weight, const float* __restrict__ bias,
              const uint4* __restrict__ Acols, float* __restrict__ ws2)
{
    __shared__ uint4 Albuf[2][1152];             // 36,864 B double buffer

    const int p = blockIdx.x;
    const int t = threadIdx.x, lane = t & 63, wv = t >> 6;
    const int nlane = lane & 15, kq = lane >> 4;
    const int o_ln  = wv * 16 + nlane;
    const float* wrow = weight + ((size_t)p * OC + o_ln) * KTOT + (kq << 3);
    const float  bb   = bias[(size_t)p * OC + o_ln];
    const uint4* ag   = Acols + (size_t)p * 3456 + wv * 64 + lane;

    f32x4 acc0 = {0.f, 0.f, 0.f, 0.f};
    f32x4 acc1 = {0.f, 0.f, 0.f, 0.f};

    // DMA one 288-k chunk (1152 uint4) into buffer BF; linear src and dst.
#define STAGE(CH, BF)                                                           \
    {                                                                           \
        _Pragma("unroll")                                                       \
        for (int rd = 0; rd < 3; ++rd) {                                        \
            __builtin_amdgcn_global_load_lds(                                   \
                (const __attribute__((address_space(1))) unsigned*)             \
                    (ag + (CH) * 1152 + rd * 384),                              \
                (__attribute__((address_space(3))) unsigned*)                   \
                    &Albuf[BF][rd * 384 + wv * 64],                             \
                16, 0, 0);                                                      \
        }                                                                       \
    }

    STAGE(0, 0)

    #pragma unroll
    for (int ch = 0; ch < 3; ++ch) {
        __syncthreads();                         // A[ch] resident
        if (ch < 2) STAGE(ch + 1, (ch + 1) & 1)  // overlap next DMA with compute

        // W burst for this chunk: 18 independent float4, line-efficient.
        float4 wn[18];
        #pragma unroll
        for (int s = 0; s < 9; ++s) {
            wn[2 * s]     = *(const float4*)(wrow + (size_t)ch * 288 + s * 32);
            wn[2 * s + 1] = *(const float4*)(wrow + (size_t)ch * 288 + s * 32 + 4);
        }
        const bf16x8* Af = (const bf16x8*)&Albuf[ch & 1][0];
        #pragma unroll
        for (int s = 0; s < 9; ++s) {
            uint4 wbu;
            wbu.x = f2bf_pk(wn[2 * s].x,     wn[2 * s].y);
            wbu.y = f2bf_pk(wn[2 * s].z,     wn[2 * s].w);
            wbu.z = f2bf_pk(wn[2 * s + 1].x, wn[2 * s + 1].y);
            wbu.w = f2bf_pk(wn[2 * s + 1].z, wn[2 * s + 1].w);
            const bf16x8 bfr = __builtin_bit_cast(bf16x8, wbu);
            const bf16x8 a0  = Af[(s * 2 + 0) * 64 + lane];
            const bf16x8 a1  = Af[(s * 2 + 1) * 64 + lane];
            acc0 = __builtin_amdgcn_mfma_f32_16x16x32_bf16(a0, bfr, acc0, 0, 0, 0);
            acc1 = __builtin_amdgcn_mfma_f32_16x16x32_bf16(a1, bfr, acc1, 0, 0, 0);
        }
    }
#undef STAGE

    // epilogue: ws2[p][b][o], full-line coalesced (validated r4/r5)
    float* wsp = ws2 + (size_t)p * (32 * OC);
    #pragma unroll
    for (int r = 0; r < 4; ++r) {
        const int brow = (kq << 2) + r;
        wsp[(size_t)brow * OC + o_ln]        = acc0[r] + bb;
        wsp[(size_t)(16 + brow) * OC + o_ln] = acc1[r] + bb;
    }
}

// ---------------------------------------------------------------------------
// Fallback main kernel (r5 path) if ws too small for Acols.
// ---------------------------------------------------------------------------
__global__ __launch_bounds__(192, 4)
void lc_mfma_fb(const float* __restrict__ x, const float* __restrict__ weight,
                const float* __restrict__ bias, float* __restrict__ ws2)
{
    __shared__ uint4 Albuf[2][384];

    const int bid = blockIdx.x;
    const int p = bid >> 1, oh = bid & 1;
    const int pi = p / OW, pj = p - pi * OW;
    const int t = threadIdx.x, lane = t & 63, wv = t >> 6;
    const int nlane = lane & 15, kq = lane >> 4;
    const int o_ln = oh * 48 + wv * 16 + nlane;
    const float* wrow = weight + ((size_t)p * OC + o_ln) * KTOT + (kq << 3);
    const float  bb   = bias[(size_t)p * OC + o_ln];
    const int bs = t & 31, kset = t >> 5;
    const int mt = bs >> 4, bl = bs & 15;
    const float* xb = x + (size_t)bs * CSTR + pi * 32 + pj;

    int wr_idx[2];
    #pragma unroll
    for (int w = 0; w < 2; ++w) {
        const int kk0 = 16 * kset + 8 * w;
        wr_idx[w] = ((kk0 >> 5) * 2 + mt) * 64 + bl + (((kk0 & 31) >> 3) << 4);
    }
    f32x4 acc0 = {0.f,0.f,0.f,0.f}, acc1 = {0.f,0.f,0.f,0.f};
    float xf[16]; float4 wn[6];

#define XLOADF(CH)                                              \
    _Pragma("unroll")                                           \
    for (int d = 0; d < 16; ++d) {                              \
        const int k  = (CH) * 96 + 16 * kset + d;               \
        const int c  = k / 9;                                   \
        const int r  = k - 9 * c;                               \
        const int di = r / 3;                                   \
        const int dj = r - 3 * di;                              \
        xf[d] = xb[c * HW_ + di * 32 + dj];                     \
    }
#define WLOADF(CH)                                                       \
    _Pragma("unroll")                                                    \
    for (int s = 0; s < 3; ++s) {                                        \
        wn[2 * s]     = *(const float4*)(wrow + (CH) * 96 + s * 32);     \
        wn[2 * s + 1] = *(const float4*)(wrow + (CH) * 96 + s * 32 + 4); \
    }
    XLOADF(0) WLOADF(0)
    #pragma unroll
    for (int ch = 0; ch < 9; ++ch) {
        const uint4 v0 = {f2bf_pk(xf[0],xf[1]),  f2bf_pk(xf[2],xf[3]),
                          f2bf_pk(xf[4],xf[5]),  f2bf_pk(xf[6],xf[7])};
        const uint4 v1 = {f2bf_pk(xf[8],xf[9]),  f2bf_pk(xf[10],xf[11]),
                          f2bf_pk(xf[12],xf[13]),f2bf_pk(xf[14],xf[15])};
        Albuf[ch & 1][wr_idx[0]] = v0;
        Albuf[ch & 1][wr_idx[1]] = v1;
        unsigned wb[12];
        #pragma unroll
        for (int s = 0; s < 3; ++s) {
            wb[4*s+0] = f2bf_pk(wn[2*s].x,   wn[2*s].y);
            wb[4*s+1] = f2bf_pk(wn[2*s].z,   wn[2*s].w);
            wb[4*s+2] = f2bf_pk(wn[2*s+1].x, wn[2*s+1].y);
            wb[4*s+3] = f2bf_pk(wn[2*s+1].z, wn[2*s+1].w);
        }
        if (ch < 8) { XLOADF(ch + 1) WLOADF(ch + 1) }
        __syncthreads();
        const bf16x8* Af = (const bf16x8*)&Albuf[ch & 1][0];
        #pragma unroll
        for (int s = 0; s < 3; ++s) {
            const bf16x8 bfr = __builtin_bit_cast(bf16x8,
                (uint4){wb[4*s], wb[4*s+1], wb[4*s+2], wb[4*s+3]});
            const bf16x8 a0 = Af[(s * 2 + 0) * 64 + lane];
            const bf16x8 a1 = Af[(s * 2 + 1) * 64 + lane];
            acc0 = __builtin_amdgcn_mfma_f32_16x16x32_bf16(a0, bfr, acc0, 0, 0, 0);
            acc1 = __builtin_amdgcn_mfma_f32_16x16x32_bf16(a1, bfr, acc1, 0, 0, 0);
        }
    }
#undef XLOADF
#undef WLOADF
    float* wsp = ws2 + (size_t)p * (32 * OC);
    #pragma unroll
    for (int r = 0; r < 4; ++r) {
        const int brow = (kq << 2) + r;
        wsp[(size_t)brow * OC + o_ln]        = acc0[r] + bb;
        wsp[(size_t)(16 + brow) * OC + o_ln] = acc1[r] + bb;
    }
}

// ws2 [900][3072] -> out [3072][900], 64x64 LDS tiles (validated r4/r5)
__global__ __launch_bounds__(256)
void lc_transpose(const float* __restrict__ ws2, float* __restrict__ out)
{
    __shared__ float tile[64][65];
    const int bo0 = blockIdx.x * 64;
    const int p0  = blockIdx.y * 64;
    const int tx  = threadIdx.x & 63;
    const int ty  = threadIdx.x >> 6;
    #pragma unroll
    for (int i = 0; i < 16; ++i) {
        const int pp = i * 4 + ty;
        if (p0 + pp < NP)
            tile[pp][tx] = ws2[(size_t)(p0 + pp) * 3072 + bo0 + tx];
    }
    __syncthreads();
    #pragma unroll
    for (int i = 0; i < 16; ++i) {
        const int bb = i * 4 + ty;
        if (p0 + tx < NP)
            out[(size_t)(bo0 + bb) * NP + p0 + tx] = tile[tx][bb];
    }
}

extern "C" void kernel_launch(void* const* d_in, const int* in_sizes, int n_in,
                              void* d_out, int out_size, void* d_ws, size_t ws_size,
                              hipStream_t stream) {
    const float* x  = (const float*)d_in[0];
    const float* w  = (const float*)d_in[1];
    const float* bi = (const float*)d_in[2];
    float* out      = (float*)d_out;

    if (ws_size >= ACOLS_BYTES + WS2_BYTES) {
        uint4* Acols = (uint4*)d_ws;
        float* ws2   = (float*)((char*)d_ws + ACOLS_BYTES);
        lc_im2col<<<dim3(360), dim3(256), 0, stream>>>(x, Acols);
        lc_mfma6<<<dim3(NP), dim3(384), 0, stream>>>(w, bi, Acols, ws2);
        lc_transpose<<<dim3(3072 / 64, (NP + 63) / 64), dim3(256), 0, stream>>>(ws2, out);
    } else {
        float* ws2 = (float*)d_ws;
        lc_mfma_fb<<<dim3(NP * 2), dim3(192), 0, stream>>>(x, w, bi, ws2);
        lc_transpose<<<dim3(3072 / 64, (NP + 63) / 64), dim3(256), 0, stream>>>(ws2, out);
    }
}